// Round 7
// baseline (715.786 us; speedup 1.0000x reference)
//
#include <hip/hip_runtime.h>
#include <math.h>

#define HDIM 64
#define HF4  16

typedef __attribute__((ext_vector_type(8))) short short8;
typedef __attribute__((ext_vector_type(4))) float floatx4;
typedef unsigned short ushort_t;

#define MFMA16(a, b, c) __builtin_amdgcn_mfma_f32_16x16x32_bf16(a, b, c, 0, 0, 0)

__device__ __forceinline__ ushort_t f2bf(float f) {
  union { float f; unsigned u; } v; v.f = f;
  unsigned u = v.u;
  return (ushort_t)((u + 0x7FFFu + ((u >> 16) & 1u)) >> 16);
}

__device__ __forceinline__ float silu1(float v) { return __fdividef(v, 1.0f + __expf(-v)); }
__device__ __forceinline__ float tanh1(float v) {
  float t = __expf(2.0f * v);
  return 1.0f - __fdividef(2.0f, t + 1.0f);
}

__device__ __forceinline__ void fma4(float4& a, float s, const float4 w) {
  a.x = fmaf(s, w.x, a.x); a.y = fmaf(s, w.y, a.y);
  a.z = fmaf(s, w.z, a.z); a.w = fmaf(s, w.w, a.w);
}
__device__ __forceinline__ float4 silu4(float4 v) {
  return make_float4(silu1(v.x), silu1(v.y), silu1(v.z), silu1(v.w));
}
__device__ __forceinline__ float4 tanh4(float4 v) {
  return make_float4(tanh1(v.x), tanh1(v.y), tanh1(v.z), tanh1(v.w));
}

__device__ __forceinline__ bool idx_is64(const int* idx32) {
  return (idx32[1] == 0) & (idx32[3] == 0) & (idx32[5] == 0) & (idx32[7] == 0);
}

// ---------------- fp32 -> bf16 conversion (x then pe, one launch) ----------------
__global__ void kcvt2(const float* __restrict__ x, const float* __restrict__ pe,
                      ushort_t* __restrict__ d, int n) {   // n = elements per tensor
  int i = (blockIdx.x * 256 + threadIdx.x) * 8;
  if (i < 2 * n) {
    const float* sp = (i < n) ? (x + i) : (pe + (i - n));
    float4 a = *(const float4*)sp;
    float4 b = *(const float4*)(sp + 4);
    union { ushort_t u[8]; uint4 v; } r;
    r.u[0] = f2bf(a.x); r.u[1] = f2bf(a.y); r.u[2] = f2bf(a.z); r.u[3] = f2bf(a.w);
    r.u[4] = f2bf(b.x); r.u[5] = f2bf(b.y); r.u[6] = f2bf(b.z); r.u[7] = f2bf(b.w);
    *(uint4*)(d + i) = r.v;
  }
}

// ---------------- receiver counting-sort: histogram -> scan -> scatter ----------------
__global__ void khist(const int* __restrict__ idx32, int* __restrict__ cnt, int E) {
  const int m = idx_is64(idx32) ? 2 : 1;
  int e = blockIdx.x * 256 + threadIdx.x;
  if (e < E) atomicAdd(&cnt[idx32[(size_t)m * (E + e)]], 1);
}

// single-block exclusive scan over n counters (n ~ 50k)
__global__ void kscan(const int* __restrict__ cnt, int* __restrict__ ofs, int n) {
  __shared__ int part[256];
  const int t = threadIdx.x;
  const int chunk = (n + 255) >> 8;
  const int lo = t * chunk, hi = min(lo + chunk, n);
  int s = 0;
  for (int i = lo; i < hi; ++i) s += cnt[i];
  part[t] = s;
  __syncthreads();
  if (t == 0) {
    int run = 0;
    for (int i = 0; i < 256; ++i) { int v = part[i]; part[i] = run; run += v; }
  }
  __syncthreads();
  int run = part[t];
  for (int i = lo; i < hi; ++i) { ofs[i] = run; run += cnt[i]; }
}

__global__ void kscat(const int* __restrict__ idx32, int* __restrict__ ofs,
                      int* __restrict__ perm, int E) {
  const int m = idx_is64(idx32) ? 2 : 1;
  int e = blockIdx.x * 256 + threadIdx.x;
  if (e < E) {
    int r = idx32[(size_t)m * (E + e)];
    int p = atomicAdd(&ofs[r], 1);
    perm[p] = e;
  }
}

// run-compressed atomic scatter: rr[0..nvalid) are receiver ids of consecutive
// sorted edges owned by this lane; av[nt][reg] activated outputs. One atomic
// flush per receiver-run instead of per edge.
__device__ __forceinline__ void scatter_runs(float* __restrict__ out, int n15,
                                             const int rr[4], const float av[4][4],
                                             int nvalid) {
  if (nvalid <= 0) return;
  int cur = rr[0];
  float s0 = av[0][0], s1 = av[1][0], s2 = av[2][0], s3 = av[3][0];
#pragma unroll
  for (int reg = 1; reg < 4; ++reg) {
    if (reg >= nvalid) break;
    if (rr[reg] == cur) {
      s0 += av[0][reg]; s1 += av[1][reg]; s2 += av[2][reg]; s3 += av[3][reg];
    } else {
      float* t = out + (size_t)cur * 64 + n15;
      unsafeAtomicAdd(t, s0); unsafeAtomicAdd(t + 16, s1);
      unsafeAtomicAdd(t + 32, s2); unsafeAtomicAdd(t + 48, s3);
      cur = rr[reg];
      s0 = av[0][reg]; s1 = av[1][reg]; s2 = av[2][reg]; s3 = av[3][reg];
    }
  }
  float* t = out + (size_t)cur * 64 + n15;
  unsafeAtomicAdd(t, s0); unsafeAtomicAdd(t + 16, s1);
  unsafeAtomicAdd(t + 32, s2); unsafeAtomicAdd(t + 48, s3);
}

// ================= merged edge kernel (receiver-sorted order) =================
// msg: state=[x_s,pe_s,x_r,pe_r,dist] (K=257), silu. pos: state=[pe_s,pe_r,dist] (K=129), tanh.
// Edges iterated via perm (sorted by receiver): receiver-row gathers go L1-hot and
// the epilogue run-compresses atomics (~3x fewer). LDS 77.5 KB -> 2 blocks/CU, grid 512.
__global__ __launch_bounds__(256, 2) void kedge(
    const ushort_t* __restrict__ xb, const ushort_t* __restrict__ peb,
    const float* __restrict__ pos, const int* __restrict__ idx32,
    const int* __restrict__ perm,
    const float* __restrict__ mw1, const float* __restrict__ mb1,
    const float* __restrict__ mw2, const float* __restrict__ mb2,
    const float* __restrict__ pw1, const float* __restrict__ pb1,
    const float* __restrict__ pw2, const float* __restrict__ pb2,
    float* __restrict__ aggr, float* __restrict__ aggrp, int E) {
  __shared__ ushort_t w1m[16384];          // 32 KB  msg w1 rows 0..255, B-frag layout
  __shared__ ushort_t w1p[8192];           // 16 KB  pos w1 rows 0..127
  __shared__ ushort_t w2m[4096];           // 8 KB
  __shared__ ushort_t w2p[4096];           // 8 KB
  __shared__ ushort_t hmat[4][1152];       // 9.2 KB: per-wave 16x72 bf16 chunk
  __shared__ int   srow[4][64];
  __shared__ int   rrow[4][64];
  __shared__ float ddv[4][64];
  __shared__ float cb1m[64], cb2m[64], wdm[64];
  __shared__ float cb1p[64], cb2p[64], wdp[64];

  for (int i = threadIdx.x; i < 257 * 64; i += 256) {
    int k = i >> 6, n = i & 63; float v = mw1[i];
    if (k < 256) w1m[(((k >> 5) * 4 + ((k >> 3) & 3)) * 64 + n) * 8 + (k & 7)] = f2bf(v);
    else wdm[n] = v;                       // dist row stays fp32
  }
  for (int i = threadIdx.x; i < 129 * 64; i += 256) {
    int k = i >> 6, n = i & 63; float v = pw1[i];
    if (k < 128) w1p[(((k >> 5) * 4 + ((k >> 3) & 3)) * 64 + n) * 8 + (k & 7)] = f2bf(v);
    else wdp[n] = v;
  }
  for (int i = threadIdx.x; i < 64 * 64; i += 256) {
    int k = i >> 6, n = i & 63;
    int off = (((k >> 5) * 4 + ((k >> 3) & 3)) * 64 + n) * 8 + (k & 7);
    w2m[off] = f2bf(mw2[i]);
    w2p[off] = f2bf(pw2[i]);
  }
  if (threadIdx.x < 64) {
    cb1m[threadIdx.x] = mb1[threadIdx.x]; cb2m[threadIdx.x] = mb2[threadIdx.x];
    cb1p[threadIdx.x] = pb1[threadIdx.x]; cb2p[threadIdx.x] = pb2[threadIdx.x];
  }
  __syncthreads();

  const int lane = threadIdx.x & 63;
  const int wv   = threadIdx.x >> 6;
  const int n15  = lane & 15;
  const int quad = lane >> 4;
  const int m = idx_is64(idx32) ? 2 : 1;
  const int gw = blockIdx.x * 4 + wv;
  ushort_t* hm = &hmat[wv][0];

  for (int base = gw * 64; base < E; base += gridDim.x * 256) {
    // ---- stage this wave's 64 sorted edges ----
    {
      int e = base + lane;
      int ec = perm[min(e, E - 1)];
      int s = idx32[(size_t)m * ec], r = idx32[(size_t)m * (E + ec)];
      srow[wv][lane] = s; rrow[wv][lane] = r;
      float dx = pos[3 * s + 0] - pos[3 * r + 0];
      float dy = pos[3 * s + 1] - pos[3 * r + 1];
      float dz = pos[3 * s + 2] - pos[3 * r + 2];
      ddv[wv][lane] = sqrtf(dx * dx + dy * dy + dz * dz);
    }
    int sm[4], rm[4];
#pragma unroll
    for (int mt = 0; mt < 4; ++mt) {
      sm[mt] = srow[wv][mt * 16 + n15];
      rm[mt] = rrow[wv][mt * 16 + n15];
    }

    // ================= message MLP phase (silu) =================
    {
      floatx4 acc[4][4];
#pragma unroll
      for (int mt = 0; mt < 4; ++mt)
#pragma unroll
        for (int reg = 0; reg < 4; ++reg) {
          float dd = ddv[wv][mt * 16 + quad * 4 + reg];
#pragma unroll
          for (int nt = 0; nt < 4; ++nt)
            acc[mt][nt][reg] = cb1m[nt * 16 + n15] + dd * wdm[nt * 16 + n15];
        }

      // layer 1: K=256 in 8 steps of 32
#pragma unroll
      for (int ks = 0; ks < 8; ++ks) {
        const int seg = ks >> 1, half = ks & 1;
        const ushort_t* sb = (seg == 0 || seg == 2) ? xb : peb;
        short8 B[4];
#pragma unroll
        for (int nt = 0; nt < 4; ++nt)
          B[nt] = *(const short8*)&w1m[((ks * 4 + quad) * 64 + nt * 16 + n15) * 8];
#pragma unroll
        for (int mt = 0; mt < 4; ++mt) {
          int row = (seg < 2) ? sm[mt] : rm[mt];
          short8 A = *(const short8*)(sb + (size_t)row * 64 + half * 32 + quad * 8);
#pragma unroll
          for (int nt = 0; nt < 4; ++nt)
            acc[mt][nt] = MFMA16(A, B[nt], acc[mt][nt]);
        }
      }

      // per-mt (16-edge) epilogue: silu -> hmat -> layer2 -> silu -> run-compressed scatter
#pragma unroll
      for (int mt = 0; mt < 4; ++mt) {
#pragma unroll
        for (int nt = 0; nt < 4; ++nt)
#pragma unroll
          for (int reg = 0; reg < 4; ++reg)
            hm[(quad * 4 + reg) * 72 + nt * 16 + n15] = f2bf(silu1(acc[mt][nt][reg]));

        floatx4 o[4];
#pragma unroll
        for (int nt = 0; nt < 4; ++nt) {
          float bv = cb2m[nt * 16 + n15];
#pragma unroll
          for (int reg = 0; reg < 4; ++reg) o[nt][reg] = bv;
        }
#pragma unroll
        for (int ks = 0; ks < 2; ++ks) {
          short8 A = *(const short8*)&hm[n15 * 72 + ks * 32 + quad * 8];
          short8 B[4];
#pragma unroll
          for (int nt = 0; nt < 4; ++nt)
            B[nt] = *(const short8*)&w2m[((ks * 4 + quad) * 64 + nt * 16 + n15) * 8];
#pragma unroll
          for (int nt = 0; nt < 4; ++nt)
            o[nt] = MFMA16(A, B[nt], o[nt]);
        }

        float av[4][4];
        int rr[4];
#pragma unroll
        for (int reg = 0; reg < 4; ++reg) {
          rr[reg] = rrow[wv][mt * 16 + quad * 4 + reg];
#pragma unroll
          for (int nt = 0; nt < 4; ++nt) av[nt][reg] = silu1(o[nt][reg]);
        }
        int nvalid = min(max(E - (base + mt * 16 + quad * 4), 0), 4);
        scatter_runs(aggr, n15, rr, av, nvalid);
      }
    }

    // ================= positional MLP phase (tanh) =================
    {
      floatx4 acc[4][4];
#pragma unroll
      for (int mt = 0; mt < 4; ++mt)
#pragma unroll
        for (int reg = 0; reg < 4; ++reg) {
          float dd = ddv[wv][mt * 16 + quad * 4 + reg];
#pragma unroll
          for (int nt = 0; nt < 4; ++nt)
            acc[mt][nt][reg] = cb1p[nt * 16 + n15] + dd * wdp[nt * 16 + n15];
        }

      // layer 1: K=128 in 4 steps of 32
#pragma unroll
      for (int ks = 0; ks < 4; ++ks) {
        const int seg = ks >> 1, half = ks & 1;
        short8 B[4];
#pragma unroll
        for (int nt = 0; nt < 4; ++nt)
          B[nt] = *(const short8*)&w1p[((ks * 4 + quad) * 64 + nt * 16 + n15) * 8];
#pragma unroll
        for (int mt = 0; mt < 4; ++mt) {
          int row = (seg == 0) ? sm[mt] : rm[mt];
          short8 A = *(const short8*)(peb + (size_t)row * 64 + half * 32 + quad * 8);
#pragma unroll
          for (int nt = 0; nt < 4; ++nt)
            acc[mt][nt] = MFMA16(A, B[nt], acc[mt][nt]);
        }
      }

#pragma unroll
      for (int mt = 0; mt < 4; ++mt) {
#pragma unroll
        for (int nt = 0; nt < 4; ++nt)
#pragma unroll
          for (int reg = 0; reg < 4; ++reg)
            hm[(quad * 4 + reg) * 72 + nt * 16 + n15] = f2bf(tanh1(acc[mt][nt][reg]));

        floatx4 o[4];
#pragma unroll
        for (int nt = 0; nt < 4; ++nt) {
          float bv = cb2p[nt * 16 + n15];
#pragma unroll
          for (int reg = 0; reg < 4; ++reg) o[nt][reg] = bv;
        }
#pragma unroll
        for (int ks = 0; ks < 2; ++ks) {
          short8 A = *(const short8*)&hm[n15 * 72 + ks * 32 + quad * 8];
          short8 B[4];
#pragma unroll
          for (int nt = 0; nt < 4; ++nt)
            B[nt] = *(const short8*)&w2p[((ks * 4 + quad) * 64 + nt * 16 + n15) * 8];
#pragma unroll
          for (int nt = 0; nt < 4; ++nt)
            o[nt] = MFMA16(A, B[nt], o[nt]);
        }

        float av[4][4];
        int rr[4];
#pragma unroll
        for (int reg = 0; reg < 4; ++reg) {
          rr[reg] = rrow[wv][mt * 16 + quad * 4 + reg];
#pragma unroll
          for (int nt = 0; nt < 4; ++nt) av[nt][reg] = tanh1(o[nt][reg]);
        }
        int nvalid = min(max(E - (base + mt * 16 + quad * 4), 0), 4);
        scatter_runs(aggrp, n15, rr, av, nvalid);
      }
    }
  }
}

// ---------------- fp32 node kernels (unchanged) ----------------
__device__ __forceinline__ void seg64(float4& a0, float4& a1,
                                      const float* p0, const float* p1,
                                      const float4* wbase, int fg) {
#pragma unroll 4
  for (int kc = 0; kc < 16; ++kc) {
    float4 s0 = ((const float4*)p0)[kc];
    float4 s1 = ((const float4*)p1)[kc];
    float4 w0 = wbase[(4 * kc + 0) * HF4 + fg];
    float4 w1 = wbase[(4 * kc + 1) * HF4 + fg];
    float4 w2 = wbase[(4 * kc + 2) * HF4 + fg];
    float4 w3 = wbase[(4 * kc + 3) * HF4 + fg];
    fma4(a0, s0.x, w0); fma4(a0, s0.y, w1); fma4(a0, s0.z, w2); fma4(a0, s0.w, w3);
    fma4(a1, s1.x, w0); fma4(a1, s1.y, w1); fma4(a1, s1.z, w2); fma4(a1, s1.w, w3);
  }
}

__device__ __forceinline__ void layer2acc(float4& o0, float4& o1,
                                          const float* h0p, const float* h1p,
                                          const float4* w2v, int fg) {
#pragma unroll 4
  for (int jc = 0; jc < 16; ++jc) {
    float4 h0 = ((const float4*)h0p)[jc];
    float4 h1 = ((const float4*)h1p)[jc];
    float4 q0 = w2v[(4 * jc + 0) * HF4 + fg];
    float4 q1 = w2v[(4 * jc + 1) * HF4 + fg];
    float4 q2 = w2v[(4 * jc + 2) * HF4 + fg];
    float4 q3 = w2v[(4 * jc + 3) * HF4 + fg];
    fma4(o0, h0.x, q0); fma4(o0, h0.y, q1); fma4(o0, h0.z, q2); fma4(o0, h0.w, q3);
    fma4(o1, h1.x, q0); fma4(o1, h1.y, q1); fma4(o1, h1.z, q2); fma4(o1, h1.w, q3);
  }
}

__global__ __launch_bounds__(256, 2) void knode_upd(
    const float* __restrict__ x, const float* __restrict__ pe,
    const float* aggr,
    const float* __restrict__ w1, const float* __restrict__ b1,
    const float* __restrict__ w2, const float* __restrict__ b2,
    float* outp, int N) {
  __shared__ float4 lw1[192 * HF4];
  __shared__ __align__(16) float lh[4][8][68];

  const float4* w1v = (const float4*)w1;
  for (int i = threadIdx.x; i < 192 * HF4; i += 256) lw1[i] = w1v[i];
  __syncthreads();

  const int lane = threadIdx.x & 63;
  const int wv   = threadIdx.x >> 6;
  const int fg   = lane & 15;
  const int eq   = lane >> 4;
  const int gw   = blockIdx.x * 4 + wv;
  const int stride = gridDim.x * 4 * 8;

  const float4 bias1 = ((const float4*)b1)[fg];
  const float4 bias2 = ((const float4*)b2)[fg];
  const float4* w2v  = (const float4*)w2;

  for (int base = gw * 8; base < N; base += stride) {
    const int n0 = base + eq, n1 = base + eq + 4;
    const int n0c = min(n0, N - 1), n1c = min(n1, N - 1);

    float4 a0 = bias1, a1 = bias1;
    seg64(a0, a1, x    + (size_t)n0c * HDIM, x    + (size_t)n1c * HDIM, lw1,             fg);
    seg64(a0, a1, pe   + (size_t)n0c * HDIM, pe   + (size_t)n1c * HDIM, lw1 + 64 * HF4,  fg);
    seg64(a0, a1, aggr + (size_t)n0c * HDIM, aggr + (size_t)n1c * HDIM, lw1 + 128 * HF4, fg);
    a0 = silu4(a0); a1 = silu4(a1);

    *(float4*)&lh[wv][eq][4 * fg]     = a0;
    *(float4*)&lh[wv][eq + 4][4 * fg] = a1;

    float4 o0 = bias2, o1 = bias2;
    layer2acc(o0, o1, &lh[wv][eq][0], &lh[wv][eq + 4][0], w2v, fg);

    if (n0 < N) *(float4*)(outp + (size_t)n0 * HDIM + 4 * fg) = o0;
    if (n1 < N) *(float4*)(outp + (size_t)n1 * HDIM + 4 * fg) = o1;
  }
}

__global__ __launch_bounds__(256, 2) void knode_upe(
    const float* __restrict__ pe,
    const float* aggrp,
    const float* __restrict__ w1, const float* __restrict__ b1,
    const float* __restrict__ w2, const float* __restrict__ b2,
    float* outp, int N) {
  __shared__ float4 lw1[128 * HF4];
  __shared__ __align__(16) float lh[4][8][68];

  const float4* w1v = (const float4*)w1;
  for (int i = threadIdx.x; i < 128 * HF4; i += 256) lw1[i] = w1v[i];
  __syncthreads();

  const int lane = threadIdx.x & 63;
  const int wv   = threadIdx.x >> 6;
  const int fg   = lane & 15;
  const int eq   = lane >> 4;
  const int gw   = blockIdx.x * 4 + wv;
  const int stride = gridDim.x * 4 * 8;

  const float4 bias1 = ((const float4*)b1)[fg];
  const float4 bias2 = ((const float4*)b2)[fg];
  const float4* w2v  = (const float4*)w2;

  for (int base = gw * 8; base < N; base += stride) {
    const int n0 = base + eq, n1 = base + eq + 4;
    const int n0c = min(n0, N - 1), n1c = min(n1, N - 1);

    float4 a0 = bias1, a1 = bias1;
    seg64(a0, a1, pe    + (size_t)n0c * HDIM, pe    + (size_t)n1c * HDIM, lw1,            fg);
    seg64(a0, a1, aggrp + (size_t)n0c * HDIM, aggrp + (size_t)n1c * HDIM, lw1 + 64 * HF4, fg);
    a0 = tanh4(a0); a1 = tanh4(a1);

    *(float4*)&lh[wv][eq][4 * fg]     = a0;
    *(float4*)&lh[wv][eq + 4][4 * fg] = a1;

    float4 o0 = bias2, o1 = bias2;
    layer2acc(o0, o1, &lh[wv][eq][0], &lh[wv][eq + 4][0], w2v, fg);
    o0 = tanh4(o0); o1 = tanh4(o1);

    if (n0 < N) *(float4*)(outp + (size_t)n0 * HDIM + 4 * fg) = o0;
    if (n1 < N) *(float4*)(outp + (size_t)n1 * HDIM + 4 * fg) = o1;
  }
}

extern "C" void kernel_launch(void* const* d_in, const int* in_sizes, int n_in,
                              void* d_out, int out_size, void* d_ws, size_t ws_size,
                              hipStream_t stream) {
  const float* x    = (const float*)d_in[0];
  const float* pos  = (const float*)d_in[1];
  const float* pe   = (const float*)d_in[2];
  const int*   eidx = (const int*)d_in[3];
  const float* msg_w1  = (const float*)d_in[4];
  const float* msg_b1  = (const float*)d_in[5];
  const float* msg_w2  = (const float*)d_in[6];
  const float* msg_b2  = (const float*)d_in[7];
  const float* mpos_w1 = (const float*)d_in[8];
  const float* mpos_b1 = (const float*)d_in[9];
  const float* mpos_w2 = (const float*)d_in[10];
  const float* mpos_b2 = (const float*)d_in[11];
  const float* upd_w1  = (const float*)d_in[12];
  const float* upd_b1  = (const float*)d_in[13];
  const float* upd_w2  = (const float*)d_in[14];
  const float* upd_b2  = (const float*)d_in[15];
  const float* upe_w1  = (const float*)d_in[16];
  const float* upe_b1  = (const float*)d_in[17];
  const float* upe_w2  = (const float*)d_in[18];
  const float* upe_b2  = (const float*)d_in[19];

  const int N = in_sizes[0] / HDIM;
  const int E = in_sizes[3] / 2;

  float* out_upd = (float*)d_out;                 // aggr accumulator, then update out
  float* out_upe = out_upd + (size_t)N * HDIM;    // aggr_pos accumulator, then update_pe out

  // workspace layout: xb | peb | perm | cnt | ofs
  ushort_t* xb  = (ushort_t*)d_ws;
  ushort_t* peb = xb + (size_t)N * HDIM;
  int* perm = (int*)(peb + (size_t)N * HDIM);
  int* cnt  = perm + E;
  int* ofs  = cnt + N;

  hipMemsetAsync(d_out, 0, (size_t)2 * N * HDIM * sizeof(float), stream);
  hipMemsetAsync(cnt, 0, (size_t)N * sizeof(int), stream);

  const int ncv = N * HDIM;
  kcvt2<<<(2 * ncv / 8 + 255) / 256, 256, 0, stream>>>(x, pe, xb, ncv);

  // receiver counting-sort -> perm
  khist<<<(E + 255) / 256, 256, 0, stream>>>(eidx, cnt, E);
  kscan<<<1, 256, 0, stream>>>(cnt, ofs, N);
  kscat<<<(E + 255) / 256, 256, 0, stream>>>(eidx, ofs, perm, E);

  kedge<<<512, 256, 0, stream>>>(xb, peb, pos, eidx, perm,
                                 msg_w1, msg_b1, msg_w2, msg_b2,
                                 mpos_w1, mpos_b1, mpos_w2, mpos_b2,
                                 out_upd, out_upe, E);
  knode_upd<<<512, 256, 0, stream>>>(x, pe, out_upd, upd_w1, upd_b1, upd_w2, upd_b2, out_upd, N);
  knode_upe<<<768, 256, 0, stream>>>(pe, out_upe, upe_w1, upe_b1, upe_w2, upe_b2, out_upe, N);
}

// Round 8
// 686.127 us; speedup vs baseline: 1.0432x; 1.0432x over previous
//
#include <hip/hip_runtime.h>
#include <math.h>

#define HDIM 64
#define HF4  16

typedef __attribute__((ext_vector_type(8))) short short8;
typedef __attribute__((ext_vector_type(4))) float floatx4;
typedef unsigned short ushort_t;

#define MFMA16(a, b, c) __builtin_amdgcn_mfma_f32_16x16x32_bf16(a, b, c, 0, 0, 0)

__device__ __forceinline__ ushort_t f2bf(float f) {
  union { float f; unsigned u; } v; v.f = f;
  unsigned u = v.u;
  return (ushort_t)((u + 0x7FFFu + ((u >> 16) & 1u)) >> 16);
}

__device__ __forceinline__ float silu1(float v) { return __fdividef(v, 1.0f + __expf(-v)); }
__device__ __forceinline__ float tanh1(float v) {
  float t = __expf(2.0f * v);
  return 1.0f - __fdividef(2.0f, t + 1.0f);
}

__device__ __forceinline__ void fma4(float4& a, float s, const float4 w) {
  a.x = fmaf(s, w.x, a.x); a.y = fmaf(s, w.y, a.y);
  a.z = fmaf(s, w.z, a.z); a.w = fmaf(s, w.w, a.w);
}
__device__ __forceinline__ float4 silu4(float4 v) {
  return make_float4(silu1(v.x), silu1(v.y), silu1(v.z), silu1(v.w));
}
__device__ __forceinline__ float4 tanh4(float4 v) {
  return make_float4(tanh1(v.x), tanh1(v.y), tanh1(v.z), tanh1(v.w));
}

// ---------------- fp32 -> bf16 conversion (x then pe, one launch) ----------------
__global__ void kcvt2(const float* __restrict__ x, const float* __restrict__ pe,
                      ushort_t* __restrict__ d, int n) {   // n = elements per tensor
  int i = (blockIdx.x * 256 + threadIdx.x) * 8;
  if (i < 2 * n) {
    const float* sp = (i < n) ? (x + i) : (pe + (i - n));
    float4 a = *(const float4*)sp;
    float4 b = *(const float4*)(sp + 4);
    union { ushort_t u[8]; uint4 v; } r;
    r.u[0] = f2bf(a.x); r.u[1] = f2bf(a.y); r.u[2] = f2bf(a.z); r.u[3] = f2bf(a.w);
    r.u[4] = f2bf(b.x); r.u[5] = f2bf(b.y); r.u[6] = f2bf(b.z); r.u[7] = f2bf(b.w);
    *(uint4*)(d + i) = r.v;
  }
}

// ================= edge kernel: message MLP via MFMA =================
// state = [x_s, pe_s, x_r, pe_r, dist] (K=257), silu. Wave tile: 64 edges x 64 out.
// 16-edge hmat keeps LDS at 54.3 KB -> 3 blocks/CU (12 waves/CU); grid 768 exact.
// (256,2): do NOT raise min-waves — R4 showed (256,3) forces VGPR 84 + scratch spills.
__global__ __launch_bounds__(256, 2) void kmsg(
    const ushort_t* __restrict__ xb, const ushort_t* __restrict__ peb,
    const float* __restrict__ pos, const int* __restrict__ idx32,
    const float* __restrict__ w1, const float* __restrict__ b1,
    const float* __restrict__ w2, const float* __restrict__ b2,
    float* __restrict__ aggr, int E) {
  __shared__ ushort_t w1b[16384];          // 32 KB, [ks(8)][quad(4)][n(64)][j(8)]
  __shared__ ushort_t w2b[4096];           // 8 KB
  __shared__ ushort_t hmat[4][1152];       // 9.2 KB: per-wave 16x72 bf16 chunk
  __shared__ int   srow[4][64];
  __shared__ int   rrow[4][64];
  __shared__ float ddv[4][64];
  __shared__ float cb1[64], cb2[64], wdv[64];

  for (int i = threadIdx.x; i < 257 * 64; i += 256) {
    int k = i >> 6, n = i & 63; float v = w1[i];
    if (k < 256) w1b[(((k >> 5) * 4 + ((k >> 3) & 3)) * 64 + n) * 8 + (k & 7)] = f2bf(v);
    else wdv[n] = v;                       // dist row stays fp32
  }
  for (int i = threadIdx.x; i < 64 * 64; i += 256) {
    int k = i >> 6, n = i & 63;
    w2b[(((k >> 5) * 4 + ((k >> 3) & 3)) * 64 + n) * 8 + (k & 7)] = f2bf(w2[i]);
  }
  if (threadIdx.x < 64) { cb1[threadIdx.x] = b1[threadIdx.x]; cb2[threadIdx.x] = b2[threadIdx.x]; }
  __syncthreads();

  const int lane = threadIdx.x & 63;
  const int wv   = threadIdx.x >> 6;
  const int n15  = lane & 15;
  const int quad = lane >> 4;
  const bool is64 = (idx32[1] == 0) & (idx32[3] == 0) & (idx32[5] == 0) & (idx32[7] == 0);
  const int m = is64 ? 2 : 1;
  const int gw = blockIdx.x * 4 + wv;
  ushort_t* hm = &hmat[wv][0];

  for (int base = gw * 64; base < E; base += gridDim.x * 256) {
    // ---- stage this wave's 64 edges (intra-wave LDS; DS pipe in-order per wave) ----
    {
      int e = base + lane, ec = min(e, E - 1);
      int s = idx32[(size_t)m * ec], r = idx32[(size_t)m * (E + ec)];
      srow[wv][lane] = s; rrow[wv][lane] = r;
      float dx = pos[3 * s + 0] - pos[3 * r + 0];
      float dy = pos[3 * s + 1] - pos[3 * r + 1];
      float dz = pos[3 * s + 2] - pos[3 * r + 2];
      ddv[wv][lane] = sqrtf(dx * dx + dy * dy + dz * dz);
    }
    int sm[4], rm[4];
#pragma unroll
    for (int mt = 0; mt < 4; ++mt) {
      sm[mt] = srow[wv][mt * 16 + n15];
      rm[mt] = rrow[wv][mt * 16 + n15];
    }

    floatx4 acc[4][4];
#pragma unroll
    for (int mt = 0; mt < 4; ++mt)
#pragma unroll
      for (int reg = 0; reg < 4; ++reg) {
        float dd = ddv[wv][mt * 16 + quad * 4 + reg];
#pragma unroll
        for (int nt = 0; nt < 4; ++nt)
          acc[mt][nt][reg] = cb1[nt * 16 + n15] + dd * wdv[nt * 16 + n15];
      }

    // layer 1: K=256 in 8 steps of 32
#pragma unroll
    for (int ks = 0; ks < 8; ++ks) {
      const int seg = ks >> 1, half = ks & 1;
      const ushort_t* sb = (seg == 0 || seg == 2) ? xb : peb;
      short8 B[4];
#pragma unroll
      for (int nt = 0; nt < 4; ++nt)
        B[nt] = *(const short8*)&w1b[((ks * 4 + quad) * 64 + nt * 16 + n15) * 8];
#pragma unroll
      for (int mt = 0; mt < 4; ++mt) {
        int row = (seg < 2) ? sm[mt] : rm[mt];
        short8 A = *(const short8*)(sb + (size_t)row * 64 + half * 32 + quad * 8);
#pragma unroll
        for (int nt = 0; nt < 4; ++nt)
          acc[mt][nt] = MFMA16(A, B[nt], acc[mt][nt]);
      }
    }

    // per-mt (16-edge) epilogue: silu -> hmat -> layer2 -> silu -> atomic scatter
#pragma unroll
    for (int mt = 0; mt < 4; ++mt) {
#pragma unroll
      for (int nt = 0; nt < 4; ++nt)
#pragma unroll
        for (int reg = 0; reg < 4; ++reg)
          hm[(quad * 4 + reg) * 72 + nt * 16 + n15] = f2bf(silu1(acc[mt][nt][reg]));

      floatx4 o[4];
#pragma unroll
      for (int nt = 0; nt < 4; ++nt) {
        float bv = cb2[nt * 16 + n15];
#pragma unroll
        for (int reg = 0; reg < 4; ++reg) o[nt][reg] = bv;
      }
#pragma unroll
      for (int ks = 0; ks < 2; ++ks) {
        short8 A = *(const short8*)&hm[n15 * 72 + ks * 32 + quad * 8];
        short8 B[4];
#pragma unroll
        for (int nt = 0; nt < 4; ++nt)
          B[nt] = *(const short8*)&w2b[((ks * 4 + quad) * 64 + nt * 16 + n15) * 8];
#pragma unroll
        for (int nt = 0; nt < 4; ++nt)
          o[nt] = MFMA16(A, B[nt], o[nt]);
      }

#pragma unroll
      for (int reg = 0; reg < 4; ++reg) {
        const int el = mt * 16 + quad * 4 + reg;
        const int e  = base + el;
        if (e < E) {
          const int rnode = rrow[wv][el];
          float* t = aggr + (size_t)rnode * 64 + n15;
#pragma unroll
          for (int nt = 0; nt < 4; ++nt)
            unsafeAtomicAdd(t + nt * 16, silu1(o[nt][reg]));
        }
      }
    }
  }
}

// ================= edge kernel: positional MLP via MFMA =================
// state = [pe_s, pe_r, dist] (K=129), tanh. LDS 37.9 KB -> 4 blocks/CU; grid 1024 exact.
__global__ __launch_bounds__(256, 2) void kpos(
    const ushort_t* __restrict__ peb,
    const float* __restrict__ pos, const int* __restrict__ idx32,
    const float* __restrict__ w1, const float* __restrict__ b1,
    const float* __restrict__ w2, const float* __restrict__ b2,
    float* __restrict__ aggrp, int E) {
  __shared__ ushort_t w1b[8192];           // 16 KB
  __shared__ ushort_t w2b[4096];           // 8 KB
  __shared__ ushort_t hmat[4][1152];       // 9.2 KB
  __shared__ int   srow[4][64];
  __shared__ int   rrow[4][64];
  __shared__ float ddv[4][64];
  __shared__ float cb1[64], cb2[64], wdv[64];

  for (int i = threadIdx.x; i < 129 * 64; i += 256) {
    int k = i >> 6, n = i & 63; float v = w1[i];
    if (k < 128) w1b[(((k >> 5) * 4 + ((k >> 3) & 3)) * 64 + n) * 8 + (k & 7)] = f2bf(v);
    else wdv[n] = v;
  }
  for (int i = threadIdx.x; i < 64 * 64; i += 256) {
    int k = i >> 6, n = i & 63;
    w2b[(((k >> 5) * 4 + ((k >> 3) & 3)) * 64 + n) * 8 + (k & 7)] = f2bf(w2[i]);
  }
  if (threadIdx.x < 64) { cb1[threadIdx.x] = b1[threadIdx.x]; cb2[threadIdx.x] = b2[threadIdx.x]; }
  __syncthreads();

  const int lane = threadIdx.x & 63;
  const int wv   = threadIdx.x >> 6;
  const int n15  = lane & 15;
  const int quad = lane >> 4;
  const bool is64 = (idx32[1] == 0) & (idx32[3] == 0) & (idx32[5] == 0) & (idx32[7] == 0);
  const int m = is64 ? 2 : 1;
  const int gw = blockIdx.x * 4 + wv;
  ushort_t* hm = &hmat[wv][0];

  for (int base = gw * 64; base < E; base += gridDim.x * 256) {
    {
      int e = base + lane, ec = min(e, E - 1);
      int s = idx32[(size_t)m * ec], r = idx32[(size_t)m * (E + ec)];
      srow[wv][lane] = s; rrow[wv][lane] = r;
      float dx = pos[3 * s + 0] - pos[3 * r + 0];
      float dy = pos[3 * s + 1] - pos[3 * r + 1];
      float dz = pos[3 * s + 2] - pos[3 * r + 2];
      ddv[wv][lane] = sqrtf(dx * dx + dy * dy + dz * dz);
    }
    int sm[4], rm[4];
#pragma unroll
    for (int mt = 0; mt < 4; ++mt) {
      sm[mt] = srow[wv][mt * 16 + n15];
      rm[mt] = rrow[wv][mt * 16 + n15];
    }

    floatx4 acc[4][4];
#pragma unroll
    for (int mt = 0; mt < 4; ++mt)
#pragma unroll
      for (int reg = 0; reg < 4; ++reg) {
        float dd = ddv[wv][mt * 16 + quad * 4 + reg];
#pragma unroll
        for (int nt = 0; nt < 4; ++nt)
          acc[mt][nt][reg] = cb1[nt * 16 + n15] + dd * wdv[nt * 16 + n15];
      }

    // layer 1: K=128 in 4 steps of 32
#pragma unroll
    for (int ks = 0; ks < 4; ++ks) {
      const int seg = ks >> 1, half = ks & 1;
      short8 B[4];
#pragma unroll
      for (int nt = 0; nt < 4; ++nt)
        B[nt] = *(const short8*)&w1b[((ks * 4 + quad) * 64 + nt * 16 + n15) * 8];
#pragma unroll
      for (int mt = 0; mt < 4; ++mt) {
        int row = (seg == 0) ? sm[mt] : rm[mt];
        short8 A = *(const short8*)(peb + (size_t)row * 64 + half * 32 + quad * 8);
#pragma unroll
        for (int nt = 0; nt < 4; ++nt)
          acc[mt][nt] = MFMA16(A, B[nt], acc[mt][nt]);
      }
    }

#pragma unroll
    for (int mt = 0; mt < 4; ++mt) {
#pragma unroll
      for (int nt = 0; nt < 4; ++nt)
#pragma unroll
        for (int reg = 0; reg < 4; ++reg)
          hm[(quad * 4 + reg) * 72 + nt * 16 + n15] = f2bf(tanh1(acc[mt][nt][reg]));

      floatx4 o[4];
#pragma unroll
      for (int nt = 0; nt < 4; ++nt) {
        float bv = cb2[nt * 16 + n15];
#pragma unroll
        for (int reg = 0; reg < 4; ++reg) o[nt][reg] = bv;
      }
#pragma unroll
      for (int ks = 0; ks < 2; ++ks) {
        short8 A = *(const short8*)&hm[n15 * 72 + ks * 32 + quad * 8];
        short8 B[4];
#pragma unroll
        for (int nt = 0; nt < 4; ++nt)
          B[nt] = *(const short8*)&w2b[((ks * 4 + quad) * 64 + nt * 16 + n15) * 8];
#pragma unroll
        for (int nt = 0; nt < 4; ++nt)
          o[nt] = MFMA16(A, B[nt], o[nt]);
      }

#pragma unroll
      for (int reg = 0; reg < 4; ++reg) {
        const int el = mt * 16 + quad * 4 + reg;
        const int e  = base + el;
        if (e < E) {
          const int rnode = rrow[wv][el];
          float* t = aggrp + (size_t)rnode * 64 + n15;
#pragma unroll
          for (int nt = 0; nt < 4; ++nt)
            unsafeAtomicAdd(t + nt * 16, tanh1(o[nt][reg]));
        }
      }
    }
  }
}

// ---------------- fp32 node kernels (LDS-trimmed: tail w1 segment stays in global/L1) ----------------
__device__ __forceinline__ void seg64(float4& a0, float4& a1,
                                      const float* p0, const float* p1,
                                      const float4* wbase, int fg) {
#pragma unroll 4
  for (int kc = 0; kc < 16; ++kc) {
    float4 s0 = ((const float4*)p0)[kc];
    float4 s1 = ((const float4*)p1)[kc];
    float4 w0 = wbase[(4 * kc + 0) * HF4 + fg];
    float4 w1 = wbase[(4 * kc + 1) * HF4 + fg];
    float4 w2 = wbase[(4 * kc + 2) * HF4 + fg];
    float4 w3 = wbase[(4 * kc + 3) * HF4 + fg];
    fma4(a0, s0.x, w0); fma4(a0, s0.y, w1); fma4(a0, s0.z, w2); fma4(a0, s0.w, w3);
    fma4(a1, s1.x, w0); fma4(a1, s1.y, w1); fma4(a1, s1.z, w2); fma4(a1, s1.w, w3);
  }
}

__device__ __forceinline__ void layer2acc(float4& o0, float4& o1,
                                          const float* h0p, const float* h1p,
                                          const float4* w2v, int fg) {
#pragma unroll 4
  for (int jc = 0; jc < 16; ++jc) {
    float4 h0 = ((const float4*)h0p)[jc];
    float4 h1 = ((const float4*)h1p)[jc];
    float4 q0 = w2v[(4 * jc + 0) * HF4 + fg];
    float4 q1 = w2v[(4 * jc + 1) * HF4 + fg];
    float4 q2 = w2v[(4 * jc + 2) * HF4 + fg];
    float4 q3 = w2v[(4 * jc + 3) * HF4 + fg];
    fma4(o0, h0.x, q0); fma4(o0, h0.y, q1); fma4(o0, h0.z, q2); fma4(o0, h0.w, q3);
    fma4(o1, h1.x, q0); fma4(o1, h1.y, q1); fma4(o1, h1.z, q2); fma4(o1, h1.w, q3);
  }
}

// [x, pe, aggr] -> 64, silu inner, no outer act. LDS 41.5 KB -> 3 blocks/CU; grid 768.
__global__ __launch_bounds__(256, 2) void knode_upd(
    const float* __restrict__ x, const float* __restrict__ pe,
    const float* aggr,
    const float* __restrict__ w1, const float* __restrict__ b1,
    const float* __restrict__ w2, const float* __restrict__ b2,
    float* outp, int N) {
  __shared__ float4 lw1[128 * HF4];        // rows 0..127 (x, pe); rows 128..191 via L1
  __shared__ __align__(16) float lh[4][8][68];

  const float4* w1v = (const float4*)w1;
  for (int i = threadIdx.x; i < 128 * HF4; i += 256) lw1[i] = w1v[i];
  __syncthreads();

  const int lane = threadIdx.x & 63;
  const int wv   = threadIdx.x >> 6;
  const int fg   = lane & 15;
  const int eq   = lane >> 4;
  const int gw   = blockIdx.x * 4 + wv;
  const int stride = gridDim.x * 4 * 8;

  const float4 bias1 = ((const float4*)b1)[fg];
  const float4 bias2 = ((const float4*)b2)[fg];
  const float4* w2v  = (const float4*)w2;

  for (int base = gw * 8; base < N; base += stride) {
    const int n0 = base + eq, n1 = base + eq + 4;
    const int n0c = min(n0, N - 1), n1c = min(n1, N - 1);

    float4 a0 = bias1, a1 = bias1;
    seg64(a0, a1, x    + (size_t)n0c * HDIM, x    + (size_t)n1c * HDIM, lw1,             fg);
    seg64(a0, a1, pe   + (size_t)n0c * HDIM, pe   + (size_t)n1c * HDIM, lw1 + 64 * HF4,  fg);
    seg64(a0, a1, aggr + (size_t)n0c * HDIM, aggr + (size_t)n1c * HDIM, w1v + 128 * HF4, fg);
    a0 = silu4(a0); a1 = silu4(a1);

    *(float4*)&lh[wv][eq][4 * fg]     = a0;
    *(float4*)&lh[wv][eq + 4][4 * fg] = a1;

    float4 o0 = bias2, o1 = bias2;
    layer2acc(o0, o1, &lh[wv][eq][0], &lh[wv][eq + 4][0], w2v, fg);

    if (n0 < N) *(float4*)(outp + (size_t)n0 * HDIM + 4 * fg) = o0;
    if (n1 < N) *(float4*)(outp + (size_t)n1 * HDIM + 4 * fg) = o1;
  }
}

// [pe, aggr_pos] -> 64, tanh inner+outer. LDS 25.1 KB -> 6 blocks/CU; grid 1536.
__global__ __launch_bounds__(256, 2) void knode_upe(
    const float* __restrict__ pe,
    const float* aggrp,
    const float* __restrict__ w1, const float* __restrict__ b1,
    const float* __restrict__ w2, const float* __restrict__ b2,
    float* outp, int N) {
  __shared__ float4 lw1[64 * HF4];         // rows 0..63 (pe); rows 64..127 via L1
  __shared__ __align__(16) float lh[4][8][68];

  const float4* w1v = (const float4*)w1;
  for (int i = threadIdx.x; i < 64 * HF4; i += 256) lw1[i] = w1v[i];
  __syncthreads();

  const int lane = threadIdx.x & 63;
  const int wv   = threadIdx.x >> 6;
  const int fg   = lane & 15;
  const int eq   = lane >> 4;
  const int gw   = blockIdx.x * 4 + wv;
  const int stride = gridDim.x * 4 * 8;

  const float4 bias1 = ((const float4*)b1)[fg];
  const float4 bias2 = ((const float4*)b2)[fg];
  const float4* w2v  = (const float4*)w2;

  for (int base = gw * 8; base < N; base += stride) {
    const int n0 = base + eq, n1 = base + eq + 4;
    const int n0c = min(n0, N - 1), n1c = min(n1, N - 1);

    float4 a0 = bias1, a1 = bias1;
    seg64(a0, a1, pe    + (size_t)n0c * HDIM, pe    + (size_t)n1c * HDIM, lw1,            fg);
    seg64(a0, a1, aggrp + (size_t)n0c * HDIM, aggrp + (size_t)n1c * HDIM, w1v + 64 * HF4, fg);
    a0 = tanh4(a0); a1 = tanh4(a1);

    *(float4*)&lh[wv][eq][4 * fg]     = a0;
    *(float4*)&lh[wv][eq + 4][4 * fg] = a1;

    float4 o0 = bias2, o1 = bias2;
    layer2acc(o0, o1, &lh[wv][eq][0], &lh[wv][eq + 4][0], w2v, fg);
    o0 = tanh4(o0); o1 = tanh4(o1);

    if (n0 < N) *(float4*)(outp + (size_t)n0 * HDIM + 4 * fg) = o0;
    if (n1 < N) *(float4*)(outp + (size_t)n1 * HDIM + 4 * fg) = o1;
  }
}

extern "C" void kernel_launch(void* const* d_in, const int* in_sizes, int n_in,
                              void* d_out, int out_size, void* d_ws, size_t ws_size,
                              hipStream_t stream) {
  const float* x    = (const float*)d_in[0];
  const float* pos  = (const float*)d_in[1];
  const float* pe   = (const float*)d_in[2];
  const int*   eidx = (const int*)d_in[3];
  const float* msg_w1  = (const float*)d_in[4];
  const float* msg_b1  = (const float*)d_in[5];
  const float* msg_w2  = (const float*)d_in[6];
  const float* msg_b2  = (const float*)d_in[7];
  const float* mpos_w1 = (const float*)d_in[8];
  const float* mpos_b1 = (const float*)d_in[9];
  const float* mpos_w2 = (const float*)d_in[10];
  const float* mpos_b2 = (const float*)d_in[11];
  const float* upd_w1  = (const float*)d_in[12];
  const float* upd_b1  = (const float*)d_in[13];
  const float* upd_w2  = (const float*)d_in[14];
  const float* upd_b2  = (const float*)d_in[15];
  const float* upe_w1  = (const float*)d_in[16];
  const float* upe_b1  = (const float*)d_in[17];
  const float* upe_w2  = (const float*)d_in[18];
  const float* upe_b2  = (const float*)d_in[19];

  const int N = in_sizes[0] / HDIM;
  const int E = in_sizes[3] / 2;

  float* out_upd = (float*)d_out;                 // aggr accumulator, then update out
  float* out_upe = out_upd + (size_t)N * HDIM;    // aggr_pos accumulator, then update_pe out

  ushort_t* xb  = (ushort_t*)d_ws;                // bf16 copies of x, pe in workspace
  ushort_t* peb = xb + (size_t)N * HDIM;

  hipMemsetAsync(d_out, 0, (size_t)2 * N * HDIM * sizeof(float), stream);

  const int ncv = N * HDIM;
  kcvt2<<<(2 * ncv / 8 + 255) / 256, 256, 0, stream>>>(x, pe, xb, ncv);

  kmsg<<<768, 256, 0, stream>>>(xb, peb, pos, eidx, msg_w1, msg_b1, msg_w2, msg_b2, out_upd, E);
  kpos<<<1024, 256, 0, stream>>>(peb, pos, eidx, mpos_w1, mpos_b1, mpos_w2, mpos_b2, out_upe, E);
  knode_upd<<<768, 256, 0, stream>>>(x, pe, out_upd, upd_w1, upd_b1, upd_w2, upd_b2, out_upd, N);
  knode_upe<<<1536, 256, 0, stream>>>(pe, out_upe, upe_w1, upe_b1, upe_w2, upe_b2, out_upe, N);
}

// Round 9
// 525.844 us; speedup vs baseline: 1.3612x; 1.3048x over previous
//
#include <hip/hip_runtime.h>
#include <math.h>

#define HDIM 64

typedef __attribute__((ext_vector_type(8))) short short8;
typedef __attribute__((ext_vector_type(4))) float floatx4;
typedef unsigned short ushort_t;

#define MFMA16(a, b, c) __builtin_amdgcn_mfma_f32_16x16x32_bf16(a, b, c, 0, 0, 0)

__device__ __forceinline__ ushort_t f2bf(float f) {
  union { float f; unsigned u; } v; v.f = f;
  unsigned u = v.u;
  return (ushort_t)((u + 0x7FFFu + ((u >> 16) & 1u)) >> 16);
}

__device__ __forceinline__ float silu1(float v) { return __fdividef(v, 1.0f + __expf(-v)); }
__device__ __forceinline__ float tanh1(float v) {
  float t = __expf(2.0f * v);
  return 1.0f - __fdividef(2.0f, t + 1.0f);
}

// ---------------- fp32 -> bf16 conversion (x then pe, one launch) ----------------
__global__ void kcvt2(const float* __restrict__ x, const float* __restrict__ pe,
                      ushort_t* __restrict__ d, int n) {   // n = elements per tensor
  int i = (blockIdx.x * 256 + threadIdx.x) * 8;
  if (i < 2 * n) {
    const float* sp = (i < n) ? (x + i) : (pe + (i - n));
    float4 a = *(const float4*)sp;
    float4 b = *(const float4*)(sp + 4);
    union { ushort_t u[8]; uint4 v; } r;
    r.u[0] = f2bf(a.x); r.u[1] = f2bf(a.y); r.u[2] = f2bf(a.z); r.u[3] = f2bf(a.w);
    r.u[4] = f2bf(b.x); r.u[5] = f2bf(b.y); r.u[6] = f2bf(b.z); r.u[7] = f2bf(b.w);
    *(uint4*)(d + i) = r.v;
  }
}

// ================= merged edge kernel (R6 verbatim — best measured) =================
// msg: state=[x_s,pe_s,x_r,pe_r,dist] (K=257), silu. pos: state=[pe_s,pe_r,dist] (K=129), tanh.
// LDS 77.5 KB -> 2 blocks/CU; grid 512 exact residency.
__global__ __launch_bounds__(256, 2) void kedge(
    const ushort_t* __restrict__ xb, const ushort_t* __restrict__ peb,
    const float* __restrict__ pos, const int* __restrict__ idx32,
    const float* __restrict__ mw1, const float* __restrict__ mb1,
    const float* __restrict__ mw2, const float* __restrict__ mb2,
    const float* __restrict__ pw1, const float* __restrict__ pb1,
    const float* __restrict__ pw2, const float* __restrict__ pb2,
    float* __restrict__ aggr, float* __restrict__ aggrp, int E) {
  __shared__ ushort_t w1m[16384];          // 32 KB  msg w1 rows 0..255, B-frag layout
  __shared__ ushort_t w1p[8192];           // 16 KB  pos w1 rows 0..127
  __shared__ ushort_t w2m[4096];           // 8 KB
  __shared__ ushort_t w2p[4096];           // 8 KB
  __shared__ ushort_t hmat[4][1152];       // 9.2 KB: per-wave 16x72 bf16 chunk
  __shared__ int   srow[4][64];
  __shared__ int   rrow[4][64];
  __shared__ float ddv[4][64];
  __shared__ float cb1m[64], cb2m[64], wdm[64];
  __shared__ float cb1p[64], cb2p[64], wdp[64];

  for (int i = threadIdx.x; i < 257 * 64; i += 256) {
    int k = i >> 6, n = i & 63; float v = mw1[i];
    if (k < 256) w1m[(((k >> 5) * 4 + ((k >> 3) & 3)) * 64 + n) * 8 + (k & 7)] = f2bf(v);
    else wdm[n] = v;                       // dist row stays fp32
  }
  for (int i = threadIdx.x; i < 129 * 64; i += 256) {
    int k = i >> 6, n = i & 63; float v = pw1[i];
    if (k < 128) w1p[(((k >> 5) * 4 + ((k >> 3) & 3)) * 64 + n) * 8 + (k & 7)] = f2bf(v);
    else wdp[n] = v;
  }
  for (int i = threadIdx.x; i < 64 * 64; i += 256) {
    int k = i >> 6, n = i & 63;
    int off = (((k >> 5) * 4 + ((k >> 3) & 3)) * 64 + n) * 8 + (k & 7);
    w2m[off] = f2bf(mw2[i]);
    w2p[off] = f2bf(pw2[i]);
  }
  if (threadIdx.x < 64) {
    cb1m[threadIdx.x] = mb1[threadIdx.x]; cb2m[threadIdx.x] = mb2[threadIdx.x];
    cb1p[threadIdx.x] = pb1[threadIdx.x]; cb2p[threadIdx.x] = pb2[threadIdx.x];
  }
  __syncthreads();

  const int lane = threadIdx.x & 63;
  const int wv   = threadIdx.x >> 6;
  const int n15  = lane & 15;
  const int quad = lane >> 4;
  const bool is64 = (idx32[1] == 0) & (idx32[3] == 0) & (idx32[5] == 0) & (idx32[7] == 0);
  const int m = is64 ? 2 : 1;
  const int gw = blockIdx.x * 4 + wv;
  ushort_t* hm = &hmat[wv][0];

  for (int base = gw * 64; base < E; base += gridDim.x * 256) {
    {
      int e = base + lane, ec = min(e, E - 1);
      int s = idx32[(size_t)m * ec], r = idx32[(size_t)m * (E + ec)];
      srow[wv][lane] = s; rrow[wv][lane] = r;
      float dx = pos[3 * s + 0] - pos[3 * r + 0];
      float dy = pos[3 * s + 1] - pos[3 * r + 1];
      float dz = pos[3 * s + 2] - pos[3 * r + 2];
      ddv[wv][lane] = sqrtf(dx * dx + dy * dy + dz * dz);
    }
    int sm[4], rm[4];
#pragma unroll
    for (int mt = 0; mt < 4; ++mt) {
      sm[mt] = srow[wv][mt * 16 + n15];
      rm[mt] = rrow[wv][mt * 16 + n15];
    }

    // ================= message MLP phase (silu) =================
    {
      floatx4 acc[4][4];
#pragma unroll
      for (int mt = 0; mt < 4; ++mt)
#pragma unroll
        for (int reg = 0; reg < 4; ++reg) {
          float dd = ddv[wv][mt * 16 + quad * 4 + reg];
#pragma unroll
          for (int nt = 0; nt < 4; ++nt)
            acc[mt][nt][reg] = cb1m[nt * 16 + n15] + dd * wdm[nt * 16 + n15];
        }

#pragma unroll
      for (int ks = 0; ks < 8; ++ks) {
        const int seg = ks >> 1, half = ks & 1;
        const ushort_t* sb = (seg == 0 || seg == 2) ? xb : peb;
        short8 B[4];
#pragma unroll
        for (int nt = 0; nt < 4; ++nt)
          B[nt] = *(const short8*)&w1m[((ks * 4 + quad) * 64 + nt * 16 + n15) * 8];
#pragma unroll
        for (int mt = 0; mt < 4; ++mt) {
          int row = (seg < 2) ? sm[mt] : rm[mt];
          short8 A = *(const short8*)(sb + (size_t)row * 64 + half * 32 + quad * 8);
#pragma unroll
          for (int nt = 0; nt < 4; ++nt)
            acc[mt][nt] = MFMA16(A, B[nt], acc[mt][nt]);
        }
      }

#pragma unroll
      for (int mt = 0; mt < 4; ++mt) {
#pragma unroll
        for (int nt = 0; nt < 4; ++nt)
#pragma unroll
          for (int reg = 0; reg < 4; ++reg)
            hm[(quad * 4 + reg) * 72 + nt * 16 + n15] = f2bf(silu1(acc[mt][nt][reg]));

        floatx4 o[4];
#pragma unroll
        for (int nt = 0; nt < 4; ++nt) {
          float bv = cb2m[nt * 16 + n15];
#pragma unroll
          for (int reg = 0; reg < 4; ++reg) o[nt][reg] = bv;
        }
#pragma unroll
        for (int ks = 0; ks < 2; ++ks) {
          short8 A = *(const short8*)&hm[n15 * 72 + ks * 32 + quad * 8];
          short8 B[4];
#pragma unroll
          for (int nt = 0; nt < 4; ++nt)
            B[nt] = *(const short8*)&w2m[((ks * 4 + quad) * 64 + nt * 16 + n15) * 8];
#pragma unroll
          for (int nt = 0; nt < 4; ++nt)
            o[nt] = MFMA16(A, B[nt], o[nt]);
        }

#pragma unroll
        for (int reg = 0; reg < 4; ++reg) {
          const int el = mt * 16 + quad * 4 + reg;
          const int e  = base + el;
          if (e < E) {
            const int rnode = rrow[wv][el];
            float* t = aggr + (size_t)rnode * 64 + n15;
#pragma unroll
            for (int nt = 0; nt < 4; ++nt)
              unsafeAtomicAdd(t + nt * 16, silu1(o[nt][reg]));
          }
        }
      }
    }

    // ================= positional MLP phase (tanh) =================
    {
      floatx4 acc[4][4];
#pragma unroll
      for (int mt = 0; mt < 4; ++mt)
#pragma unroll
        for (int reg = 0; reg < 4; ++reg) {
          float dd = ddv[wv][mt * 16 + quad * 4 + reg];
#pragma unroll
          for (int nt = 0; nt < 4; ++nt)
            acc[mt][nt][reg] = cb1p[nt * 16 + n15] + dd * wdp[nt * 16 + n15];
        }

#pragma unroll
      for (int ks = 0; ks < 4; ++ks) {
        const int seg = ks >> 1, half = ks & 1;
        short8 B[4];
#pragma unroll
        for (int nt = 0; nt < 4; ++nt)
          B[nt] = *(const short8*)&w1p[((ks * 4 + quad) * 64 + nt * 16 + n15) * 8];
#pragma unroll
        for (int mt = 0; mt < 4; ++mt) {
          int row = (seg == 0) ? sm[mt] : rm[mt];
          short8 A = *(const short8*)(peb + (size_t)row * 64 + half * 32 + quad * 8);
#pragma unroll
          for (int nt = 0; nt < 4; ++nt)
            acc[mt][nt] = MFMA16(A, B[nt], acc[mt][nt]);
        }
      }

#pragma unroll
      for (int mt = 0; mt < 4; ++mt) {
#pragma unroll
        for (int nt = 0; nt < 4; ++nt)
#pragma unroll
          for (int reg = 0; reg < 4; ++reg)
            hm[(quad * 4 + reg) * 72 + nt * 16 + n15] = f2bf(tanh1(acc[mt][nt][reg]));

        floatx4 o[4];
#pragma unroll
        for (int nt = 0; nt < 4; ++nt) {
          float bv = cb2p[nt * 16 + n15];
#pragma unroll
          for (int reg = 0; reg < 4; ++reg) o[nt][reg] = bv;
        }
#pragma unroll
        for (int ks = 0; ks < 2; ++ks) {
          short8 A = *(const short8*)&hm[n15 * 72 + ks * 32 + quad * 8];
          short8 B[4];
#pragma unroll
          for (int nt = 0; nt < 4; ++nt)
            B[nt] = *(const short8*)&w2p[((ks * 4 + quad) * 64 + nt * 16 + n15) * 8];
#pragma unroll
          for (int nt = 0; nt < 4; ++nt)
            o[nt] = MFMA16(A, B[nt], o[nt]);
        }

#pragma unroll
        for (int reg = 0; reg < 4; ++reg) {
          const int el = mt * 16 + quad * 4 + reg;
          const int e  = base + el;
          if (e < E) {
            const int rnode = rrow[wv][el];
            float* t = aggrp + (size_t)rnode * 64 + n15;
#pragma unroll
            for (int nt = 0; nt < 4; ++nt)
              unsafeAtomicAdd(t + nt * 16, tanh1(o[nt][reg]));
          }
        }
      }
    }
  }
}

// ================= node kernel: update MLP via MFMA =================
// update_in = [x, pe, aggr] (K=192), silu inner, NO outer act. 64-node x 64-out wave tile.
// Sequential rows (coalesced), no atomics. aggr aliases outp: each wave reads its rows
// fully (layer-1) before writing them (rows owned exclusively by one wave).
__global__ __launch_bounds__(256, 2) void knode_upd(
    const ushort_t* __restrict__ xb, const ushort_t* __restrict__ peb,
    const float* aggr,
    const float* __restrict__ w1, const float* __restrict__ b1,
    const float* __restrict__ w2, const float* __restrict__ b2,
    float* outp, int N) {
  __shared__ ushort_t w1b[12288];          // 24 KB: 192 k-rows, B-frag layout
  __shared__ ushort_t w2b[4096];           // 8 KB
  __shared__ ushort_t hmat[4][4608];       // 36.9 KB: full 64x72 per wave
  __shared__ float cb1[64], cb2[64];

  for (int i = threadIdx.x; i < 192 * 64; i += 256) {
    int k = i >> 6, n = i & 63;
    w1b[(((k >> 5) * 4 + ((k >> 3) & 3)) * 64 + n) * 8 + (k & 7)] = f2bf(w1[i]);
  }
  for (int i = threadIdx.x; i < 64 * 64; i += 256) {
    int k = i >> 6, n = i & 63;
    w2b[(((k >> 5) * 4 + ((k >> 3) & 3)) * 64 + n) * 8 + (k & 7)] = f2bf(w2[i]);
  }
  if (threadIdx.x < 64) { cb1[threadIdx.x] = b1[threadIdx.x]; cb2[threadIdx.x] = b2[threadIdx.x]; }
  __syncthreads();

  const int lane = threadIdx.x & 63;
  const int wv   = threadIdx.x >> 6;
  const int n15  = lane & 15;
  const int quad = lane >> 4;
  const int gw   = blockIdx.x * 4 + wv;
  ushort_t* hm = &hmat[wv][0];

  for (int base = gw * 64; base < N; base += gridDim.x * 256) {
    floatx4 acc[4][4];
#pragma unroll
    for (int mt = 0; mt < 4; ++mt)
#pragma unroll
      for (int nt = 0; nt < 4; ++nt) {
        float bv = cb1[nt * 16 + n15];
#pragma unroll
        for (int reg = 0; reg < 4; ++reg) acc[mt][nt][reg] = bv;
      }

    // layer 1: K=192 in 6 steps of 32 (seg 0: x, 1: pe, 2: aggr fp32->bf16)
#pragma unroll
    for (int ks = 0; ks < 6; ++ks) {
      const int seg = ks >> 1, half = ks & 1;
      short8 B[4];
#pragma unroll
      for (int nt = 0; nt < 4; ++nt)
        B[nt] = *(const short8*)&w1b[((ks * 4 + quad) * 64 + nt * 16 + n15) * 8];
#pragma unroll
      for (int mt = 0; mt < 4; ++mt) {
        int row = min(base + mt * 16 + n15, N - 1);
        short8 A;
        if (seg == 0) {
          A = *(const short8*)(xb + (size_t)row * 64 + half * 32 + quad * 8);
        } else if (seg == 1) {
          A = *(const short8*)(peb + (size_t)row * 64 + half * 32 + quad * 8);
        } else {
          const float* ap = aggr + (size_t)row * 64 + half * 32 + quad * 8;
          float4 f0 = *(const float4*)ap;
          float4 f1 = *(const float4*)(ap + 4);
          union { ushort_t u[8]; short8 s; } pk;
          pk.u[0] = f2bf(f0.x); pk.u[1] = f2bf(f0.y); pk.u[2] = f2bf(f0.z); pk.u[3] = f2bf(f0.w);
          pk.u[4] = f2bf(f1.x); pk.u[5] = f2bf(f1.y); pk.u[6] = f2bf(f1.z); pk.u[7] = f2bf(f1.w);
          A = pk.s;
        }
#pragma unroll
        for (int nt = 0; nt < 4; ++nt)
          acc[mt][nt] = MFMA16(A, B[nt], acc[mt][nt]);
      }
    }

    // epilogue 1: silu -> bf16 h-matrix (full 64x72)
#pragma unroll
    for (int mt = 0; mt < 4; ++mt)
#pragma unroll
      for (int nt = 0; nt < 4; ++nt)
#pragma unroll
        for (int reg = 0; reg < 4; ++reg)
          hm[(mt * 16 + quad * 4 + reg) * 72 + nt * 16 + n15] =
              f2bf(silu1(acc[mt][nt][reg]));

    // layer 2: K=64 in 2 steps; no outer activation
    floatx4 o[4][4];
#pragma unroll
    for (int mt = 0; mt < 4; ++mt)
#pragma unroll
      for (int nt = 0; nt < 4; ++nt) {
        float bv = cb2[nt * 16 + n15];
#pragma unroll
        for (int reg = 0; reg < 4; ++reg) o[mt][nt][reg] = bv;
      }
#pragma unroll
    for (int ks = 0; ks < 2; ++ks) {
      short8 B[4];
#pragma unroll
      for (int nt = 0; nt < 4; ++nt)
        B[nt] = *(const short8*)&w2b[((ks * 4 + quad) * 64 + nt * 16 + n15) * 8];
#pragma unroll
      for (int mt = 0; mt < 4; ++mt) {
        short8 A = *(const short8*)&hm[(mt * 16 + n15) * 72 + ks * 32 + quad * 8];
#pragma unroll
        for (int nt = 0; nt < 4; ++nt)
          o[mt][nt] = MFMA16(A, B[nt], o[mt][nt]);
      }
    }

#pragma unroll
    for (int mt = 0; mt < 4; ++mt)
#pragma unroll
      for (int reg = 0; reg < 4; ++reg) {
        const int row = base + mt * 16 + quad * 4 + reg;
        if (row < N) {
#pragma unroll
          for (int nt = 0; nt < 4; ++nt)
            outp[(size_t)row * 64 + nt * 16 + n15] = o[mt][nt][reg];
        }
      }
  }
}

// ================= node kernel: pe update MLP via MFMA =================
// upe_in = [pe, aggr_pos] (K=128), tanh inner AND outer.
__global__ __launch_bounds__(256, 2) void knode_upe(
    const ushort_t* __restrict__ peb,
    const float* aggrp,
    const float* __restrict__ w1, const float* __restrict__ b1,
    const float* __restrict__ w2, const float* __restrict__ b2,
    float* outp, int N) {
  __shared__ ushort_t w1b[8192];           // 16 KB: 128 k-rows
  __shared__ ushort_t w2b[4096];           // 8 KB
  __shared__ ushort_t hmat[4][4608];       // 36.9 KB
  __shared__ float cb1[64], cb2[64];

  for (int i = threadIdx.x; i < 128 * 64; i += 256) {
    int k = i >> 6, n = i & 63;
    w1b[(((k >> 5) * 4 + ((k >> 3) & 3)) * 64 + n) * 8 + (k & 7)] = f2bf(w1[i]);
  }
  for (int i = threadIdx.x; i < 64 * 64; i += 256) {
    int k = i >> 6, n = i & 63;
    w2b[(((k >> 5) * 4 + ((k >> 3) & 3)) * 64 + n) * 8 + (k & 7)] = f2bf(w2[i]);
  }
  if (threadIdx.x < 64) { cb1[threadIdx.x] = b1[threadIdx.x]; cb2[threadIdx.x] = b2[threadIdx.x]; }
  __syncthreads();

  const int lane = threadIdx.x & 63;
  const int wv   = threadIdx.x >> 6;
  const int n15  = lane & 15;
  const int quad = lane >> 4;
  const int gw   = blockIdx.x * 4 + wv;
  ushort_t* hm = &hmat[wv][0];

  for (int base = gw * 64; base < N; base += gridDim.x * 256) {
    floatx4 acc[4][4];
#pragma unroll
    for (int mt = 0; mt < 4; ++mt)
#pragma unroll
      for (int nt = 0; nt < 4; ++nt) {
        float bv = cb1[nt * 16 + n15];
#pragma unroll
        for (int reg = 0; reg < 4; ++reg) acc[mt][nt][reg] = bv;
      }

    // layer 1: K=128 in 4 steps of 32 (seg 0: pe, 1: aggrp fp32->bf16)
#pragma unroll
    for (int ks = 0; ks < 4; ++ks) {
      const int seg = ks >> 1, half = ks & 1;
      short8 B[4];
#pragma unroll
      for (int nt = 0; nt < 4; ++nt)
        B[nt] = *(const short8*)&w1b[((ks * 4 + quad) * 64 + nt * 16 + n15) * 8];
#pragma unroll
      for (int mt = 0; mt < 4; ++mt) {
        int row = min(base + mt * 16 + n15, N - 1);
        short8 A;
        if (seg == 0) {
          A = *(const short8*)(peb + (size_t)row * 64 + half * 32 + quad * 8);
        } else {
          const float* ap = aggrp + (size_t)row * 64 + half * 32 + quad * 8;
          float4 f0 = *(const float4*)ap;
          float4 f1 = *(const float4*)(ap + 4);
          union { ushort_t u[8]; short8 s; } pk;
          pk.u[0] = f2bf(f0.x); pk.u[1] = f2bf(f0.y); pk.u[2] = f2bf(f0.z); pk.u[3] = f2bf(f0.w);
          pk.u[4] = f2bf(f1.x); pk.u[5] = f2bf(f1.y); pk.u[6] = f2bf(f1.z); pk.u[7] = f2bf(f1.w);
          A = pk.s;
        }
#pragma unroll
        for (int nt = 0; nt < 4; ++nt)
          acc[mt][nt] = MFMA16(A, B[nt], acc[mt][nt]);
      }
    }

    // epilogue 1: tanh -> bf16 h-matrix
#pragma unroll
    for (int mt = 0; mt < 4; ++mt)
#pragma unroll
      for (int nt = 0; nt < 4; ++nt)
#pragma unroll
        for (int reg = 0; reg < 4; ++reg)
          hm[(mt * 16 + quad * 4 + reg) * 72 + nt * 16 + n15] =
              f2bf(tanh1(acc[mt][nt][reg]));

    // layer 2: K=64 in 2 steps; outer tanh
    floatx4 o[4][4];
#pragma unroll
    for (int mt = 0; mt < 4; ++mt)
#pragma unroll
      for (int nt = 0; nt < 4; ++nt) {
        float bv = cb2[nt * 16 + n15];
#pragma unroll
        for (int reg = 0; reg < 4; ++reg) o[mt][nt][reg] = bv;
      }
#pragma unroll
    for (int ks = 0; ks < 2; ++ks) {
      short8 B[4];
#pragma unroll
      for (int nt = 0; nt < 4; ++nt)
        B[nt] = *(const short8*)&w2b[((ks * 4 + quad) * 64 + nt * 16 + n15) * 8];
#pragma unroll
      for (int mt = 0; mt < 4; ++mt) {
        short8 A = *(const short8*)&hm[(mt * 16 + n15) * 72 + ks * 32 + quad * 8];
#pragma unroll
        for (int nt = 0; nt < 4; ++nt)
          o[mt][nt] = MFMA16(A, B[nt], o[mt][nt]);
      }
    }

#pragma unroll
    for (int mt = 0; mt < 4; ++mt)
#pragma unroll
      for (int reg = 0; reg < 4; ++reg) {
        const int row = base + mt * 16 + quad * 4 + reg;
        if (row < N) {
#pragma unroll
          for (int nt = 0; nt < 4; ++nt)
            outp[(size_t)row * 64 + nt * 16 + n15] = tanh1(o[mt][nt][reg]);
        }
      }
  }
}

extern "C" void kernel_launch(void* const* d_in, const int* in_sizes, int n_in,
                              void* d_out, int out_size, void* d_ws, size_t ws_size,
                              hipStream_t stream) {
  const float* x    = (const float*)d_in[0];
  const float* pos  = (const float*)d_in[1];
  const float* pe   = (const float*)d_in[2];
  const int*   eidx = (const int*)d_in[3];
  const float* msg_w1  = (const float*)d_in[4];
  const float* msg_b1  = (const float*)d_in[5];
  const float* msg_w2  = (const float*)d_in[6];
  const float* msg_b2  = (const float*)d_in[7];
  const float* mpos_w1 = (const float*)d_in[8];
  const float* mpos_b1 = (const float*)d_in[9];
  const float* mpos_w2 = (const float*)d_in[10];
  const float* mpos_b2 = (const float*)d_in[11];
  const float* upd_w1  = (const float*)d_in[12];
  const float* upd_b1  = (const float*)d_in[13];
  const float* upd_w2  = (const float*)d_in[14];
  const float* upd_b2  = (const float*)d_in[15];
  const float* upe_w1  = (const float*)d_in[16];
  const float* upe_b1  = (const float*)d_in[17];
  const float* upe_w2  = (const float*)d_in[18];
  const float* upe_b2  = (const float*)d_in[19];

  const int N = in_sizes[0] / HDIM;
  const int E = in_sizes[3] / 2;

  float* out_upd = (float*)d_out;                 // aggr accumulator, then update out
  float* out_upe = out_upd + (size_t)N * HDIM;    // aggr_pos accumulator, then update_pe out

  ushort_t* xb  = (ushort_t*)d_ws;                // bf16 copies of x, pe in workspace
  ushort_t* peb = xb + (size_t)N * HDIM;

  hipMemsetAsync(d_out, 0, (size_t)2 * N * HDIM * sizeof(float), stream);

  const int ncv = N * HDIM;
  kcvt2<<<(2 * ncv / 8 + 255) / 256, 256, 0, stream>>>(x, pe, xb, ncv);

  kedge<<<512, 256, 0, stream>>>(xb, peb, pos, eidx,
                                 msg_w1, msg_b1, msg_w2, msg_b2,
                                 mpos_w1, mpos_b1, mpos_w2, mpos_b2,
                                 out_upd, out_upe, E);

  // node kernels: one 64-node tile per wave -> grid = ceil(ceil(N/64)/4)
  const int ntiles = (N + 63) / 64;
  const int ngrid  = (ntiles + 3) / 4;
  knode_upd<<<ngrid, 256, 0, stream>>>(xb, peb, out_upd, upd_w1, upd_b1, upd_w2, upd_b2,
                                       out_upd, N);
  knode_upe<<<ngrid, 256, 0, stream>>>(peb, out_upe, upe_w1, upe_b1, upe_w2, upe_b2,
                                       out_upe, N);
}